// Round 17
// baseline (223.618 us; speedup 1.0000x reference)
//
#include <hip/hip_runtime.h>
#include <math.h>

#define DM 768
#define DI 1536
#define NS 16
#define LL 2048
#define MROWS 4096
#define CH 32
#define NC 64

using bf16x8 = __attribute__((ext_vector_type(8))) short;
using f32x4 = __attribute__((ext_vector_type(4))) float;

__device__ __forceinline__ float4 ld4(const float* p) { return *(const float4*)p; }

__device__ __forceinline__ unsigned short f2bf(float f) {
  unsigned int u = __float_as_uint(f);
  u += 0x7fff + ((u >> 16) & 1);  // RNE
  return (unsigned short)(u >> 16);
}
__device__ __forceinline__ float b2f(unsigned short s) {
  return __uint_as_float(((unsigned int)s) << 16);
}

__device__ __forceinline__ void gload16(const void* g, void* l) {
  __builtin_amdgcn_global_load_lds((const __attribute__((address_space(1))) void*)g,
                                   (__attribute__((address_space(3))) void*)l, 16, 0, 0);
}

// ---------------- fused fp32 -> bf16 weight converter (3 weights, 1 launch) ----------------
#define N4_IN 589824
#define N4_CAT 638976
#define N4_OUT 294912
__global__ __launch_bounds__(256) void cvt_all(const float* __restrict__ ipw,
                                               const float* __restrict__ dtw,
                                               const float* __restrict__ xpw,
                                               const float* __restrict__ opw,
                                               unsigned short* __restrict__ d_in4,
                                               unsigned short* __restrict__ d_cat,
                                               unsigned short* __restrict__ d_out4) {
  int i = blockIdx.x * 256 + threadIdx.x;
  if (i < N4_IN) {
    float4 v = ld4(ipw + (size_t)i * 4);
    ushort4 o = {f2bf(v.x), f2bf(v.y), f2bf(v.z), f2bf(v.w)};
    *(ushort4*)(d_in4 + (size_t)i * 4) = o;
  } else if (i < N4_IN + N4_CAT) {
    int j = i - N4_IN;
    int row = j / 384;
    int col = (j % 384) * 4;
    ushort4 o = {0, 0, 0, 0};
    if (row < 1536) {
      float4 v = ld4(dtw + (size_t)row * DI + col);
      o = {f2bf(v.x), f2bf(v.y), f2bf(v.z), f2bf(v.w)};
    } else if (row < 1568) {
      float4 v = ld4(xpw + (size_t)(row - 1536) * DI + col);
      o = {f2bf(v.x), f2bf(v.y), f2bf(v.z), f2bf(v.w)};
    }
    *(ushort4*)(d_cat + (size_t)j * 4) = o;
  } else if (i < N4_IN + N4_CAT + N4_OUT) {
    int j = i - N4_IN - N4_CAT;
    float4 v = ld4(opw + (size_t)j * 4);
    ushort4 o = {f2bf(v.x), f2bf(v.y), f2bf(v.z), f2bf(v.w)};
    *(ushort4*)(d_out4 + (size_t)j * 4) = o;
  }
}

// ---------------- RMSNorm -> bf16 ----------------
__global__ __launch_bounds__(256) void rmsnorm_kernel(const float* __restrict__ x,
                                                      const float* __restrict__ w,
                                                      unsigned short* __restrict__ xn) {
  int row = blockIdx.x;
  const float* xr = x + (size_t)row * DM;
  unsigned short* xo = xn + (size_t)row * DM;
  int tid = threadIdx.x;
  float v0 = xr[tid], v1 = xr[tid + 256], v2 = xr[tid + 512];
  float ss = v0 * v0 + v1 * v1 + v2 * v2;
#pragma unroll
  for (int o = 32; o > 0; o >>= 1) ss += __shfl_xor(ss, o, 64);
  __shared__ float red[4];
  if ((tid & 63) == 0) red[tid >> 6] = ss;
  __syncthreads();
  float tot = red[0] + red[1] + red[2] + red[3];
  float sc = rsqrtf(tot * (1.0f / 768.0f) + 1.1920928955078125e-07f);
  xo[tid] = f2bf(v0 * sc * w[tid]);
  xo[tid + 256] = f2bf(v1 * sc * w[tid + 256]);
  xo[tid + 512] = f2bf(v2 * sc * w[tid + 512]);
}

// ---------------- bf16 MFMA NT-GEMM: dbuf LDS + counted vmcnt + raw barriers ----------------
// R15: 2-phase vmcnt(0) drain is on the critical path (MfmaUtil 13%, busy 56%). T4 fix:
// issue next tile's 4 gloads, then s_waitcnt vmcnt(4) = wait ONLY current tile's loads;
// next tile's loads stay in flight across the raw s_barrier. Buffer overwritten at t+1
// is the one read at t: each wave's MFMA->ds_read dependency completes its reads before
// it reaches the trailing barrier, so the overwrite is race-free.
// All GEMMs 64x64 (NCH=16 -> exactly 4 gloads/thread -> literal vmcnt(4)); LDS 2x16KB.
template <int EPI, int BM, int BN>
__global__ __launch_bounds__(256) void mfma_gemm(const unsigned short* __restrict__ A,
                                                 const unsigned short* __restrict__ Bw,
                                                 const float* __restrict__ bias,
                                                 const float* __restrict__ resid,
                                                 void* __restrict__ o0v,
                                                 void* __restrict__ o1v, int K, int gx) {
  constexpr int NFI = BM / 32;
  constexpr int NFJ = BN / 32;
  constexpr int NCH = (BM + BN) / 8;  // 16 for 64x64 -> 4 gloads/thread/stage
  __shared__ unsigned short As[2][BM * 64];
  __shared__ unsigned short Bs[2][BN * 64];
  int tid = threadIdx.x;
  int lane = tid & 63, w = tid >> 6;
  int wr = w >> 1, wc = w & 1;

  // XCD-chunked bijective swizzle (nwg % 8 == 0 for all launches here)
  int nwg = gx * gridDim.y;
  int orig = blockIdx.y * gx + blockIdx.x;
  int q = nwg >> 3;
  int swz = (orig & 7) * q + (orig >> 3);
  int bm = (swz / gx) * BM, bn = (swz % gx) * BN;

  f32x4 acc[NFI][NFJ];
#pragma unroll
  for (int i = 0; i < NFI; i++)
#pragma unroll
    for (int j = 0; j < NFJ; j++) acc[i][j] = (f32x4){0.f, 0.f, 0.f, 0.f};

  const unsigned short* Ab = A + (size_t)bm * K;
  const unsigned short* Bb = Bw + (size_t)bn * K;
  int lrow = lane >> 3;                          // 0..7
  int kof = ((lane & 7) ^ lrow) * 8;             // inverse-swizzled global source chunk

  auto stage = [&](int buf, int k0) {
#pragma unroll
    for (int ch = w; ch < NCH; ch += 4) {
      if (ch < BM / 8) {
        int row = ch * 8 + lrow;
        gload16(Ab + (size_t)row * K + k0 + kof, &As[buf][ch * 512]);
      } else {
        int row = (ch - BM / 8) * 8 + lrow;
        gload16(Bb + (size_t)row * K + k0 + kof, &Bs[buf][(ch - BM / 8) * 512]);
      }
    }
  };
  auto compute = [&](int buf) {
#pragma unroll
    for (int kk = 0; kk < 2; kk++) {
      int sa = (((kk * 4) + (lane >> 4)) ^ (lane & 7)) * 8;  // swizzled read slot
      bf16x8 af[NFI], bfr[NFJ];
#pragma unroll
      for (int i = 0; i < NFI; i++) {
        int arow = wr * (BM / 2) + i * 16 + (lane & 15);
        af[i] = *(const bf16x8*)&As[buf][arow * 64 + sa];
      }
#pragma unroll
      for (int j = 0; j < NFJ; j++) {
        int brow = wc * (BN / 2) + j * 16 + (lane & 15);
        bfr[j] = *(const bf16x8*)&Bs[buf][brow * 64 + sa];
      }
#pragma unroll
      for (int i = 0; i < NFI; i++)
#pragma unroll
        for (int j = 0; j < NFJ; j++)
          acc[i][j] = __builtin_amdgcn_mfma_f32_16x16x32_bf16(af[i], bfr[j], acc[i][j], 0, 0, 0);
    }
  };

  int nk = K >> 6;
  stage(0, 0);
  for (int t = 0; t < nk; t++) {
    if (t + 1 < nk) {
      stage((t + 1) & 1, (t + 1) << 6);                  // next tile's 4 loads fly on
      asm volatile("s_waitcnt vmcnt(4)" ::: "memory");   // wait current tile only
    } else {
      asm volatile("s_waitcnt vmcnt(0)" ::: "memory");   // last tile: full drain
    }
    __builtin_amdgcn_s_barrier();   // tile t visible to all waves
    compute(t & 1);
    __builtin_amdgcn_s_barrier();   // all waves done reading tile t (reads consumed by MFMA deps)
  }

#pragma unroll
  for (int i = 0; i < NFI; i++) {
#pragma unroll
    for (int j = 0; j < NFJ; j++) {
      int row0 = bm + wr * (BM / 2) + i * 16 + (lane >> 4) * 4;
      int col = bn + wc * (BN / 2) + j * 16 + (lane & 15);
#pragma unroll
      for (int r = 0; r < 4; r++) {
        float v = acc[i][j][r];
        int row = row0 + r;
        if (EPI == 0) {
          unsigned short* xb = (unsigned short*)o0v;
          unsigned short* z = (unsigned short*)o1v;
          if (col < DI) xb[(size_t)row * DI + col] = f2bf(v);
          else z[(size_t)row * DI + col - DI] = f2bf(v);
        } else if (EPI == 1) {
          float* delta = (float*)o0v;
          float* bc = (float*)o1v;
          if (col < DI) {
            v += bias[col];
            v = (v > 20.0f) ? v : log1pf(expf(v));
            delta[(size_t)row * DI + col] = v;
          } else if (col < DI + 2 * NS) {
            bc[(size_t)row * 32 + col - DI] = v;
          }
        } else {
          float* out = (float*)o0v;
          out[(size_t)row * DM + col] = v + resid[(size_t)row * DM + col];
        }
      }
    }
  }
}

// ---------------- depthwise causal conv (K=4) + bias + SiLU, bf16 in/out ----------------
__global__ __launch_bounds__(192) void conv_silu_kernel(const unsigned short* __restrict__ xb,
                                                        const float* __restrict__ cw,
                                                        const float* __restrict__ cb,
                                                        unsigned short* __restrict__ u) {
  int d = (blockIdx.x * 192 + threadIdx.x) << 2;
  int m = blockIdx.y;
  int t = m & (LL - 1);
  float4 w0 = ld4(cw + d * 4);
  float4 w1 = ld4(cw + d * 4 + 4);
  float4 w2 = ld4(cw + d * 4 + 8);
  float4 w3 = ld4(cw + d * 4 + 12);
  float4 acc = {cb[d], cb[d + 1], cb[d + 2], cb[d + 3]};
#pragma unroll
  for (int tap = 0; tap < 4; tap++) {
    int dt_ = 3 - tap;
    if (t >= dt_) {
      ushort4 xv = *(const ushort4*)(xb + (size_t)(m - dt_) * DI + d);
      float wx = (tap == 0) ? w0.x : (tap == 1) ? w0.y : (tap == 2) ? w0.z : w0.w;
      float wy = (tap == 0) ? w1.x : (tap == 1) ? w1.y : (tap == 2) ? w1.z : w1.w;
      float wz = (tap == 0) ? w2.x : (tap == 1) ? w2.y : (tap == 2) ? w2.z : w2.w;
      float ww = (tap == 0) ? w3.x : (tap == 1) ? w3.y : (tap == 2) ? w3.z : w3.w;
      acc.x += b2f(xv.x) * wx;
      acc.y += b2f(xv.y) * wy;
      acc.z += b2f(xv.z) * wz;
      acc.w += b2f(xv.w) * ww;
    }
  }
  ushort4 o = {f2bf(acc.x / (1.0f + __expf(-acc.x))), f2bf(acc.y / (1.0f + __expf(-acc.y))),
               f2bf(acc.z / (1.0f + __expf(-acc.z))), f2bf(acc.w / (1.0f + __expf(-acc.w)))};
  *(ushort4*)(u + (size_t)m * DI + d) = o;
}

// ---------------- chunked selective scan (CH=32, NC=64 -> 768 blocks/pass) ----------------
__global__ __launch_bounds__(256) void scan_pass1(const float* __restrict__ delta,
                                                  const unsigned short* __restrict__ u,
                                                  const float* __restrict__ bc,
                                                  const float* __restrict__ A_log,
                                                  float* __restrict__ chunkP,
                                                  float* __restrict__ chunkS) {
  int d = blockIdx.x * 256 + threadIdx.x;
  int c = blockIdx.y;
  int b = blockIdx.z;
  float Acoef[NS];
#pragma unroll
  for (int n = 0; n < NS; n++) Acoef[n] = -__expf(A_log[d * NS + n]);
  __shared__ float sB[CH][NS];
  const float* bcb = bc + (size_t)(b * LL + c * CH) * 32;
  for (int i = threadIdx.x; i < CH * NS; i += 256) sB[i >> 4][i & 15] = bcb[(i >> 4) * 32 + (i & 15)];
  __syncthreads();
  float P[NS], S[NS];
#pragma unroll
  for (int n = 0; n < NS; n++) { P[n] = 1.f; S[n] = 0.f; }
  int m0 = b * LL + c * CH;
  for (int tt = 0; tt < CH; tt++) {
    size_t off = (size_t)(m0 + tt) * DI + d;
    float dl = delta[off];
    float ut = b2f(u[off]);
    float dlu = dl * ut;
#pragma unroll
    for (int n = 0; n < NS; n++) {
      float dA = __expf(dl * Acoef[n]);
      S[n] = dA * S[n] + dlu * sB[tt][n];
      P[n] *= dA;
    }
  }
  size_t base = ((size_t)(b * NC + c) * NS) * DI + d;
#pragma unroll
  for (int n = 0; n < NS; n++) {
    chunkP[base + (size_t)n * DI] = P[n];
    chunkS[base + (size_t)n * DI] = S[n];
  }
}

__global__ __launch_bounds__(256) void scan_pass2(const float* __restrict__ chunkP,
                                                  float* __restrict__ chunkS) {
  int id = blockIdx.x * 256 + threadIdx.x;
  int d = id % DI;
  int n = (id / DI) % NS;
  int b = id / (DI * NS);
  float h = 0.f;
  for (int c = 0; c < NC; c++) {
    size_t idx = ((size_t)(b * NC + c) * NS + n) * DI + d;
    float p = chunkP[idx];
    float s = chunkS[idx];
    chunkS[idx] = h;
    h = p * h + s;
  }
}

__global__ __launch_bounds__(256) void scan_pass3(const float* __restrict__ delta,
                                                  const unsigned short* __restrict__ u,
                                                  const float* __restrict__ bc,
                                                  const float* __restrict__ hIn,
                                                  const float* __restrict__ A_log,
                                                  const float* __restrict__ D_skip,
                                                  const unsigned short* __restrict__ z,
                                                  unsigned short* __restrict__ yg) {
  int d = blockIdx.x * 256 + threadIdx.x;
  int c = blockIdx.y;
  int b = blockIdx.z;
  float Acoef[NS];
#pragma unroll
  for (int n = 0; n < NS; n++) Acoef[n] = -__expf(A_log[d * NS + n]);
  float Dsk = D_skip[d];
  __shared__ float sBC[CH][32];
  const float* bcb = bc + (size_t)(b * LL + c * CH) * 32;
  for (int i = threadIdx.x; i < CH * 32; i += 256) sBC[i >> 5][i & 31] = bcb[i];
  __syncthreads();
  float h[NS];
  size_t base = ((size_t)(b * NC + c) * NS) * DI + d;
#pragma unroll
  for (int n = 0; n < NS; n++) h[n] = hIn[base + (size_t)n * DI];
  int m0 = b * LL + c * CH;
  for (int tt = 0; tt < CH; tt++) {
    size_t m = (size_t)(m0 + tt);
    size_t off = m * DI + d;
    float dl = delta[off];
    float ut = b2f(u[off]);
    float dlu = dl * ut;
    float yt = 0.f;
#pragma unroll
    for (int n = 0; n < NS; n++) {
      float dA = __expf(dl * Acoef[n]);
      h[n] = dA * h[n] + dlu * sBC[tt][n];
      yt += h[n] * sBC[tt][16 + n];
    }
    float zv = b2f(z[m * DI + d]);
    float sz = zv / (1.0f + __expf(-zv));
    yg[m * DI + d] = f2bf((yt + ut * Dsk) * sz);
  }
}

extern "C" void kernel_launch(void* const* d_in, const int* in_sizes, int n_in,
                              void* d_out, int out_size, void* d_ws, size_t ws_size,
                              hipStream_t stream) {
  const float* x = (const float*)d_in[0];
  const float* norm_w = (const float*)d_in[1];
  const float* in_proj_w = (const float*)d_in[2];
  const float* conv_w = (const float*)d_in[3];
  const float* conv_b = (const float*)d_in[4];
  const float* x_proj_w = (const float*)d_in[5];
  const float* dt_proj_w = (const float*)d_in[6];
  const float* dt_proj_b = (const float*)d_in[7];
  const float* A_log = (const float*)d_in[8];
  const float* D_skip = (const float*)d_in[9];
  const float* out_proj_w = (const float*)d_in[10];
  float* out = (float*)d_out;

  float* ws = (float*)d_ws;
  unsigned short* xb_bf = (unsigned short*)ws;                 // -> 3,145,728 fl
  unsigned short* z_bf = (unsigned short*)(ws + 3145728);      // -> 6,291,456
  unsigned short* u_bf = (unsigned short*)(ws + 6291456);      // -> 9,437,184
  float* delta = ws + 9437184;                                 // -> 15,728,640
  unsigned short* ygbf = (unsigned short*)(ws + 15728640);     // -> 17,301,504
  unsigned short* wbf_in = (unsigned short*)(ws + 18874368);   // -> 20,054,016
  unsigned short* wbf_cat = (unsigned short*)(ws + 20054016);  // -> 21,331,968
  unsigned short* wbf_out = (unsigned short*)(ws + 21331968);  // -> 21,921,792
  float* chunkP = ws + 21921792;                               // -> 25,067,520
  float* chunkS = ws + 25067520;                               // -> 28,213,248 (112.9 MB)
  unsigned short* xn_bf = (unsigned short*)d_out;  // 4096*768 bf16
  float* bcb = (float*)d_out + 1572864;            // 4096*32 f32

  cvt_all<<<5953, 256, 0, stream>>>(in_proj_w, dt_proj_w, x_proj_w, out_proj_w,
                                    wbf_in, wbf_cat, wbf_out);

  rmsnorm_kernel<<<4096, 256, 0, stream>>>(x, norm_w, xn_bf);

  // xb|z = rmsnorm(x) @ in_proj_w^T   (M=4096, N=3072, K=768), 64x64 -> 3072 blocks
  mfma_gemm<0, 64, 64><<<dim3(48, 64), 256, 0, stream>>>(xn_bf, wbf_in, nullptr, nullptr,
                                                         xb_bf, z_bf, DM, 48);

  conv_silu_kernel<<<dim3(2, 4096), 192, 0, stream>>>(xb_bf, conv_w, conv_b, u_bf);

  // delta|bc = u @ [dt_proj_w; x_proj_w]^T  (M=4096, N=1664, K=1536), 64x64 -> 1664 blocks
  mfma_gemm<1, 64, 64><<<dim3(26, 64), 256, 0, stream>>>(u_bf, wbf_cat, dt_proj_b, nullptr,
                                                         delta, bcb, DI, 26);

  scan_pass1<<<dim3(6, NC, 2), 256, 0, stream>>>(delta, u_bf, bcb, A_log, chunkP, chunkS);
  scan_pass2<<<192, 256, 0, stream>>>(chunkP, chunkS);
  scan_pass3<<<dim3(6, NC, 2), 256, 0, stream>>>(delta, u_bf, bcb, chunkS, A_log, D_skip,
                                                 z_bf, ygbf);

  // out = yg @ out_proj_w^T + x  (M=4096, N=768, K=1536), 64x64 -> 768 blocks
  mfma_gemm<2, 64, 64><<<dim3(12, 64), 256, 0, stream>>>(ygbf, wbf_out, nullptr, x, out,
                                                         nullptr, DI, 12);
}

// Round 18
// 220.538 us; speedup vs baseline: 1.0140x; 1.0140x over previous
//
#include <hip/hip_runtime.h>
#include <math.h>

#define DM 768
#define DI 1536
#define NS 16
#define LL 2048
#define MROWS 4096
#define CH 32
#define NC 64

using bf16x8 = __attribute__((ext_vector_type(8))) short;
using f32x4 = __attribute__((ext_vector_type(4))) float;

__device__ __forceinline__ float4 ld4(const float* p) { return *(const float4*)p; }

__device__ __forceinline__ unsigned short f2bf(float f) {
  unsigned int u = __float_as_uint(f);
  u += 0x7fff + ((u >> 16) & 1);  // RNE
  return (unsigned short)(u >> 16);
}
__device__ __forceinline__ float b2f(unsigned short s) {
  return __uint_as_float(((unsigned int)s) << 16);
}

__device__ __forceinline__ void gload16(const void* g, void* l) {
  __builtin_amdgcn_global_load_lds((const __attribute__((address_space(1))) void*)g,
                                   (__attribute__((address_space(3))) void*)l, 16, 0, 0);
}

// ---------------- fused prep: fp32->bf16 weights (3 tensors) + RMSNorm, one launch ----------------
#define N4_IN 589824
#define N4_CAT 638976
#define N4_OUT 294912
#define CVT_BLOCKS 5953
__global__ __launch_bounds__(256) void prep_kernel(const float* __restrict__ ipw,
                                                   const float* __restrict__ dtw,
                                                   const float* __restrict__ xpw,
                                                   const float* __restrict__ opw,
                                                   unsigned short* __restrict__ d_in4,
                                                   unsigned short* __restrict__ d_cat,
                                                   unsigned short* __restrict__ d_out4,
                                                   const float* __restrict__ x,
                                                   const float* __restrict__ nw,
                                                   unsigned short* __restrict__ xn) {
  int blk = blockIdx.x;
  int tid = threadIdx.x;
  if (blk >= CVT_BLOCKS) {
    // RMSNorm row
    int row = blk - CVT_BLOCKS;
    const float* xr = x + (size_t)row * DM;
    unsigned short* xo = xn + (size_t)row * DM;
    float v0 = xr[tid], v1 = xr[tid + 256], v2 = xr[tid + 512];
    float ss = v0 * v0 + v1 * v1 + v2 * v2;
#pragma unroll
    for (int o = 32; o > 0; o >>= 1) ss += __shfl_xor(ss, o, 64);
    __shared__ float red[4];
    if ((tid & 63) == 0) red[tid >> 6] = ss;
    __syncthreads();
    float tot = red[0] + red[1] + red[2] + red[3];
    float sc = rsqrtf(tot * (1.0f / 768.0f) + 1.1920928955078125e-07f);
    xo[tid] = f2bf(v0 * sc * nw[tid]);
    xo[tid + 256] = f2bf(v1 * sc * nw[tid + 256]);
    xo[tid + 512] = f2bf(v2 * sc * nw[tid + 512]);
    return;
  }
  int i = blk * 256 + tid;
  if (i < N4_IN) {
    float4 v = ld4(ipw + (size_t)i * 4);
    ushort4 o = {f2bf(v.x), f2bf(v.y), f2bf(v.z), f2bf(v.w)};
    *(ushort4*)(d_in4 + (size_t)i * 4) = o;
  } else if (i < N4_IN + N4_CAT) {
    int j = i - N4_IN;
    int row = j / 384;
    int col = (j % 384) * 4;
    ushort4 o = {0, 0, 0, 0};
    if (row < 1536) {
      float4 v = ld4(dtw + (size_t)row * DI + col);
      o = {f2bf(v.x), f2bf(v.y), f2bf(v.z), f2bf(v.w)};
    } else if (row < 1568) {
      float4 v = ld4(xpw + (size_t)(row - 1536) * DI + col);
      o = {f2bf(v.x), f2bf(v.y), f2bf(v.z), f2bf(v.w)};
    }
    *(ushort4*)(d_cat + (size_t)j * 4) = o;
  } else if (i < N4_IN + N4_CAT + N4_OUT) {
    int j = i - N4_IN - N4_CAT;
    float4 v = ld4(opw + (size_t)j * 4);
    ushort4 o = {f2bf(v.x), f2bf(v.y), f2bf(v.z), f2bf(v.w)};
    *(ushort4*)(d_out4 + (size_t)j * 4) = o;
  }
}

// ---------------- bf16 MFMA NT-GEMM: 3-buffer LDS, 2-deep prefetch, counted vmcnt ----------------
// R17: 1-deep vmcnt(4) null -- one tile's compute (~150-300cy) < load latency (~900cy HBM).
// 2-deep: stage(t+2) so each tile's loads have 2 tile-times in flight. Per iter:
//   [barrier]  all waves finished compute(t-1) -> buf[(t+2)%3]==buf[(t-1)%3] safe to overwrite
//   stage(t+2) 4 gloads/thread
//   vmcnt(8)   FIFO: allows t+1,t+2's 8 loads outstanding -> tile t's loads complete
//   [barrier]  cross-wave visibility of tile t
//   compute(t)
// 64x64 tiles: NCH=16 -> exactly 4 gloads/thread -> literal counts 8/4/0. LDS 3x16KB=48KB.
template <int EPI, int BM, int BN>
__global__ __launch_bounds__(256) void mfma_gemm(const unsigned short* __restrict__ A,
                                                 const unsigned short* __restrict__ Bw,
                                                 const float* __restrict__ bias,
                                                 const float* __restrict__ resid,
                                                 void* __restrict__ o0v,
                                                 void* __restrict__ o1v, int K, int gx) {
  constexpr int NFI = BM / 32;
  constexpr int NFJ = BN / 32;
  constexpr int NCH = (BM + BN) / 8;  // 16 for 64x64
  __shared__ unsigned short As[3][BM * 64];
  __shared__ unsigned short Bs[3][BN * 64];
  int tid = threadIdx.x;
  int lane = tid & 63, w = tid >> 6;
  int wr = w >> 1, wc = w & 1;

  // XCD-chunked bijective swizzle (nwg % 8 == 0 for all launches here)
  int nwg = gx * gridDim.y;
  int orig = blockIdx.y * gx + blockIdx.x;
  int q = nwg >> 3;
  int swz = (orig & 7) * q + (orig >> 3);
  int bm = (swz / gx) * BM, bn = (swz % gx) * BN;

  f32x4 acc[NFI][NFJ];
#pragma unroll
  for (int i = 0; i < NFI; i++)
#pragma unroll
    for (int j = 0; j < NFJ; j++) acc[i][j] = (f32x4){0.f, 0.f, 0.f, 0.f};

  const unsigned short* Ab = A + (size_t)bm * K;
  const unsigned short* Bb = Bw + (size_t)bn * K;
  int lrow = lane >> 3;                          // 0..7
  int kof = ((lane & 7) ^ lrow) * 8;             // inverse-swizzled global source chunk

  auto stage = [&](int buf, int k0) {
#pragma unroll
    for (int ch = w; ch < NCH; ch += 4) {
      if (ch < BM / 8) {
        int row = ch * 8 + lrow;
        gload16(Ab + (size_t)row * K + k0 + kof, &As[buf][ch * 512]);
      } else {
        int row = (ch - BM / 8) * 8 + lrow;
        gload16(Bb + (size_t)row * K + k0 + kof, &Bs[buf][(ch - BM / 8) * 512]);
      }
    }
  };
  auto compute = [&](int buf) {
#pragma unroll
    for (int kk = 0; kk < 2; kk++) {
      int sa = (((kk * 4) + (lane >> 4)) ^ (lane & 7)) * 8;  // swizzled read slot
      bf16x8 af[NFI], bfr[NFJ];
#pragma unroll
      for (int i = 0; i < NFI; i++) {
        int arow = wr * (BM / 2) + i * 16 + (lane & 15);
        af[i] = *(const bf16x8*)&As[buf][arow * 64 + sa];
      }
#pragma unroll
      for (int j = 0; j < NFJ; j++) {
        int brow = wc * (BN / 2) + j * 16 + (lane & 15);
        bfr[j] = *(const bf16x8*)&Bs[buf][brow * 64 + sa];
      }
#pragma unroll
      for (int i = 0; i < NFI; i++)
#pragma unroll
        for (int j = 0; j < NFJ; j++)
          acc[i][j] = __builtin_amdgcn_mfma_f32_16x16x32_bf16(af[i], bfr[j], acc[i][j], 0, 0, 0);
    }
  };

  int nk = K >> 6;
  stage(0, 0);
  stage(1, 64);
  int buf = 0;
  for (int t = 0; t < nk; t++) {
    __builtin_amdgcn_s_barrier();  // all waves done reading buf[(t-1)%3] == stage target
    if (t + 2 < nk) {
      int b2 = buf + 2; if (b2 >= 3) b2 -= 3;
      stage(b2, (t + 2) << 6);
      asm volatile("s_waitcnt vmcnt(8)" ::: "memory");   // tile t's loads done (FIFO)
    } else if (t + 1 < nk) {
      asm volatile("s_waitcnt vmcnt(4)" ::: "memory");
    } else {
      asm volatile("s_waitcnt vmcnt(0)" ::: "memory");
    }
    __builtin_amdgcn_s_barrier();  // tile t visible to all waves
    compute(buf);
    buf = (buf == 2) ? 0 : buf + 1;
  }

#pragma unroll
  for (int i = 0; i < NFI; i++) {
#pragma unroll
    for (int j = 0; j < NFJ; j++) {
      int row0 = bm + wr * (BM / 2) + i * 16 + (lane >> 4) * 4;
      int col = bn + wc * (BN / 2) + j * 16 + (lane & 15);
#pragma unroll
      for (int r = 0; r < 4; r++) {
        float v = acc[i][j][r];
        int row = row0 + r;
        if (EPI == 0) {
          unsigned short* xb = (unsigned short*)o0v;
          unsigned short* z = (unsigned short*)o1v;
          if (col < DI) xb[(size_t)row * DI + col] = f2bf(v);
          else z[(size_t)row * DI + col - DI] = f2bf(v);
        } else if (EPI == 1) {
          unsigned short* delta = (unsigned short*)o0v;  // bf16 delta
          float* bc = (float*)o1v;
          if (col < DI) {
            v += bias[col];
            v = (v > 20.0f) ? v : log1pf(expf(v));
            delta[(size_t)row * DI + col] = f2bf(v);
          } else if (col < DI + 2 * NS) {
            bc[(size_t)row * 32 + col - DI] = v;
          }
        } else {
          float* out = (float*)o0v;
          out[(size_t)row * DM + col] = v + resid[(size_t)row * DM + col];
        }
      }
    }
  }
}

// ---------------- depthwise causal conv (K=4) + bias + SiLU, bf16 in/out ----------------
__global__ __launch_bounds__(192) void conv_silu_kernel(const unsigned short* __restrict__ xb,
                                                        const float* __restrict__ cw,
                                                        const float* __restrict__ cb,
                                                        unsigned short* __restrict__ u) {
  int d = (blockIdx.x * 192 + threadIdx.x) << 2;
  int m = blockIdx.y;
  int t = m & (LL - 1);
  float4 w0 = ld4(cw + d * 4);
  float4 w1 = ld4(cw + d * 4 + 4);
  float4 w2 = ld4(cw + d * 4 + 8);
  float4 w3 = ld4(cw + d * 4 + 12);
  float4 acc = {cb[d], cb[d + 1], cb[d + 2], cb[d + 3]};
#pragma unroll
  for (int tap = 0; tap < 4; tap++) {
    int dt_ = 3 - tap;
    if (t >= dt_) {
      ushort4 xv = *(const ushort4*)(xb + (size_t)(m - dt_) * DI + d);
      float wx = (tap == 0) ? w0.x : (tap == 1) ? w0.y : (tap == 2) ? w0.z : w0.w;
      float wy = (tap == 0) ? w1.x : (tap == 1) ? w1.y : (tap == 2) ? w1.z : w1.w;
      float wz = (tap == 0) ? w2.x : (tap == 1) ? w2.y : (tap == 2) ? w2.z : w2.w;
      float ww = (tap == 0) ? w3.x : (tap == 1) ? w3.y : (tap == 2) ? w3.z : w3.w;
      acc.x += b2f(xv.x) * wx;
      acc.y += b2f(xv.y) * wy;
      acc.z += b2f(xv.z) * wz;
      acc.w += b2f(xv.w) * ww;
    }
  }
  ushort4 o = {f2bf(acc.x / (1.0f + __expf(-acc.x))), f2bf(acc.y / (1.0f + __expf(-acc.y))),
               f2bf(acc.z / (1.0f + __expf(-acc.z))), f2bf(acc.w / (1.0f + __expf(-acc.w)))};
  *(ushort4*)(u + (size_t)m * DI + d) = o;
}

// ---------------- chunked selective scan (CH=32, NC=64 -> 768 blocks/pass), bf16 delta ----------------
__global__ __launch_bounds__(256) void scan_pass1(const unsigned short* __restrict__ delta,
                                                  const unsigned short* __restrict__ u,
                                                  const float* __restrict__ bc,
                                                  const float* __restrict__ A_log,
                                                  float* __restrict__ chunkP,
                                                  float* __restrict__ chunkS) {
  int d = blockIdx.x * 256 + threadIdx.x;
  int c = blockIdx.y;
  int b = blockIdx.z;
  float Acoef[NS];
#pragma unroll
  for (int n = 0; n < NS; n++) Acoef[n] = -__expf(A_log[d * NS + n]);
  __shared__ float sB[CH][NS];
  const float* bcb = bc + (size_t)(b * LL + c * CH) * 32;
  for (int i = threadIdx.x; i < CH * NS; i += 256) sB[i >> 4][i & 15] = bcb[(i >> 4) * 32 + (i & 15)];
  __syncthreads();
  float P[NS], S[NS];
#pragma unroll
  for (int n = 0; n < NS; n++) { P[n] = 1.f; S[n] = 0.f; }
  int m0 = b * LL + c * CH;
  for (int tt = 0; tt < CH; tt++) {
    size_t off = (size_t)(m0 + tt) * DI + d;
    float dl = b2f(delta[off]);
    float ut = b2f(u[off]);
    float dlu = dl * ut;
#pragma unroll
    for (int n = 0; n < NS; n++) {
      float dA = __expf(dl * Acoef[n]);
      S[n] = dA * S[n] + dlu * sB[tt][n];
      P[n] *= dA;
    }
  }
  size_t base = ((size_t)(b * NC + c) * NS) * DI + d;
#pragma unroll
  for (int n = 0; n < NS; n++) {
    chunkP[base + (size_t)n * DI] = P[n];
    chunkS[base + (size_t)n * DI] = S[n];
  }
}

__global__ __launch_bounds__(256) void scan_pass2(const float* __restrict__ chunkP,
                                                  float* __restrict__ chunkS) {
  int id = blockIdx.x * 256 + threadIdx.x;
  int d = id % DI;
  int n = (id / DI) % NS;
  int b = id / (DI * NS);
  float h = 0.f;
  for (int c = 0; c < NC; c++) {
    size_t idx = ((size_t)(b * NC + c) * NS + n) * DI + d;
    float p = chunkP[idx];
    float s = chunkS[idx];
    chunkS[idx] = h;
    h = p * h + s;
  }
}

__global__ __launch_bounds__(256) void scan_pass3(const unsigned short* __restrict__ delta,
                                                  const unsigned short* __restrict__ u,
                                                  const float* __restrict__ bc,
                                                  const float* __restrict__ hIn,
                                                  const float* __restrict__ A_log,
                                                  const float* __restrict__ D_skip,
                                                  const unsigned short* __restrict__ z,
                                                  unsigned short* __restrict__ yg) {
  int d = blockIdx.x * 256 + threadIdx.x;
  int c = blockIdx.y;
  int b = blockIdx.z;
  float Acoef[NS];
#pragma unroll
  for (int n = 0; n < NS; n++) Acoef[n] = -__expf(A_log[d * NS + n]);
  float Dsk = D_skip[d];
  __shared__ float sBC[CH][32];
  const float* bcb = bc + (size_t)(b * LL + c * CH) * 32;
  for (int i = threadIdx.x; i < CH * 32; i += 256) sBC[i >> 5][i & 31] = bcb[i];
  __syncthreads();
  float h[NS];
  size_t base = ((size_t)(b * NC + c) * NS) * DI + d;
#pragma unroll
  for (int n = 0; n < NS; n++) h[n] = hIn[base + (size_t)n * DI];
  int m0 = b * LL + c * CH;
  for (int tt = 0; tt < CH; tt++) {
    size_t m = (size_t)(m0 + tt);
    size_t off = m * DI + d;
    float dl = b2f(delta[off]);
    float ut = b2f(u[off]);
    float dlu = dl * ut;
    float yt = 0.f;
#pragma unroll
    for (int n = 0; n < NS; n++) {
      float dA = __expf(dl * Acoef[n]);
      h[n] = dA * h[n] + dlu * sBC[tt][n];
      yt += h[n] * sBC[tt][16 + n];
    }
    float zv = b2f(z[m * DI + d]);
    float sz = zv / (1.0f + __expf(-zv));
    yg[m * DI + d] = f2bf((yt + ut * Dsk) * sz);
  }
}

extern "C" void kernel_launch(void* const* d_in, const int* in_sizes, int n_in,
                              void* d_out, int out_size, void* d_ws, size_t ws_size,
                              hipStream_t stream) {
  const float* x = (const float*)d_in[0];
  const float* norm_w = (const float*)d_in[1];
  const float* in_proj_w = (const float*)d_in[2];
  const float* conv_w = (const float*)d_in[3];
  const float* conv_b = (const float*)d_in[4];
  const float* x_proj_w = (const float*)d_in[5];
  const float* dt_proj_w = (const float*)d_in[6];
  const float* dt_proj_b = (const float*)d_in[7];
  const float* A_log = (const float*)d_in[8];
  const float* D_skip = (const float*)d_in[9];
  const float* out_proj_w = (const float*)d_in[10];
  float* out = (float*)d_out;

  float* ws = (float*)d_ws;
  unsigned short* xb_bf = (unsigned short*)ws;                 // -> 3,145,728 fl
  unsigned short* z_bf = (unsigned short*)(ws + 3145728);      // -> 6,291,456
  unsigned short* u_bf = (unsigned short*)(ws + 6291456);      // -> 9,437,184
  unsigned short* delta_bf = (unsigned short*)(ws + 9437184);  // bf16 now; slot -> 15,728,640
  unsigned short* ygbf = (unsigned short*)(ws + 15728640);     // -> 17,301,504
  unsigned short* wbf_in = (unsigned short*)(ws + 18874368);   // -> 20,054,016
  unsigned short* wbf_cat = (unsigned short*)(ws + 20054016);  // -> 21,331,968
  unsigned short* wbf_out = (unsigned short*)(ws + 21331968);  // -> 21,921,792
  float* chunkP = ws + 21921792;                               // -> 25,067,520
  float* chunkS = ws + 25067520;                               // -> 28,213,248 (112.9 MB)
  unsigned short* xn_bf = (unsigned short*)d_out;  // 4096*768 bf16
  float* bcb = (float*)d_out + 1572864;            // 4096*32 f32

  prep_kernel<<<CVT_BLOCKS + 4096, 256, 0, stream>>>(in_proj_w, dt_proj_w, x_proj_w,
                                                     out_proj_w, wbf_in, wbf_cat, wbf_out,
                                                     x, norm_w, xn_bf);

  // xb|z = rmsnorm(x) @ in_proj_w^T   (M=4096, N=3072, K=768), 64x64 -> 3072 blocks
  mfma_gemm<0, 64, 64><<<dim3(48, 64), 256, 0, stream>>>(xn_bf, wbf_in, nullptr, nullptr,
                                                         xb_bf, z_bf, DM, 48);

  conv_silu_kernel<<<dim3(2, 4096), 192, 0, stream>>>(xb_bf, conv_w, conv_b, u_bf);

  // delta|bc = u @ [dt_proj_w; x_proj_w]^T  (M=4096, N=1664, K=1536), 64x64 -> 1664 blocks
  mfma_gemm<1, 64, 64><<<dim3(26, 64), 256, 0, stream>>>(u_bf, wbf_cat, dt_proj_b, nullptr,
                                                         delta_bf, bcb, DI, 26);

  scan_pass1<<<dim3(6, NC, 2), 256, 0, stream>>>(delta_bf, u_bf, bcb, A_log, chunkP, chunkS);
  scan_pass2<<<192, 256, 0, stream>>>(chunkP, chunkS);
  scan_pass3<<<dim3(6, NC, 2), 256, 0, stream>>>(delta_bf, u_bf, bcb, chunkS, A_log, D_skip,
                                                 z_bf, ygbf);

  // out = yg @ out_proj_w^T + x  (M=4096, N=768, K=1536), 64x64 -> 768 blocks
  mfma_gemm<2, 64, 64><<<dim3(12, 64), 256, 0, stream>>>(ygbf, wbf_out, nullptr, x, out,
                                                         nullptr, DI, 12);
}

// Round 19
// 217.681 us; speedup vs baseline: 1.0273x; 1.0131x over previous
//
#include <hip/hip_runtime.h>
#include <math.h>

#define DM 768
#define DI 1536
#define NS 16
#define LL 2048
#define MROWS 4096
#define CH 32
#define NC 64

using bf16x8 = __attribute__((ext_vector_type(8))) short;
using f32x4 = __attribute__((ext_vector_type(4))) float;

__device__ __forceinline__ float4 ld4(const float* p) { return *(const float4*)p; }

__device__ __forceinline__ unsigned short f2bf(float f) {
  unsigned int u = __float_as_uint(f);
  u += 0x7fff + ((u >> 16) & 1);  // RNE
  return (unsigned short)(u >> 16);
}
__device__ __forceinline__ float b2f(unsigned short s) {
  return __uint_as_float(((unsigned int)s) << 16);
}

__device__ __forceinline__ void gload16(const void* g, void* l) {
  __builtin_amdgcn_global_load_lds((const __attribute__((address_space(1))) void*)g,
                                   (__attribute__((address_space(3))) void*)l, 16, 0, 0);
}

// ---------------- fused prep: fp32->bf16 weights (3 tensors) + RMSNorm, one launch ----------------
#define N4_IN 589824
#define N4_CAT 638976
#define N4_OUT 294912
#define CVT_BLOCKS 5953
__global__ __launch_bounds__(256) void prep_kernel(const float* __restrict__ ipw,
                                                   const float* __restrict__ dtw,
                                                   const float* __restrict__ xpw,
                                                   const float* __restrict__ opw,
                                                   unsigned short* __restrict__ d_in4,
                                                   unsigned short* __restrict__ d_cat,
                                                   unsigned short* __restrict__ d_out4,
                                                   const float* __restrict__ x,
                                                   const float* __restrict__ nw,
                                                   unsigned short* __restrict__ xn) {
  int blk = blockIdx.x;
  int tid = threadIdx.x;
  if (blk >= CVT_BLOCKS) {
    int row = blk - CVT_BLOCKS;
    const float* xr = x + (size_t)row * DM;
    unsigned short* xo = xn + (size_t)row * DM;
    float v0 = xr[tid], v1 = xr[tid + 256], v2 = xr[tid + 512];
    float ss = v0 * v0 + v1 * v1 + v2 * v2;
#pragma unroll
    for (int o = 32; o > 0; o >>= 1) ss += __shfl_xor(ss, o, 64);
    __shared__ float red[4];
    if ((tid & 63) == 0) red[tid >> 6] = ss;
    __syncthreads();
    float tot = red[0] + red[1] + red[2] + red[3];
    float sc = rsqrtf(tot * (1.0f / 768.0f) + 1.1920928955078125e-07f);
    xo[tid] = f2bf(v0 * sc * nw[tid]);
    xo[tid + 256] = f2bf(v1 * sc * nw[tid + 256]);
    xo[tid + 512] = f2bf(v2 * sc * nw[tid + 512]);
    return;
  }
  int i = blk * 256 + tid;
  if (i < N4_IN) {
    float4 v = ld4(ipw + (size_t)i * 4);
    ushort4 o = {f2bf(v.x), f2bf(v.y), f2bf(v.z), f2bf(v.w)};
    *(ushort4*)(d_in4 + (size_t)i * 4) = o;
  } else if (i < N4_IN + N4_CAT) {
    int j = i - N4_IN;
    int row = j / 384;
    int col = (j % 384) * 4;
    ushort4 o = {0, 0, 0, 0};
    if (row < 1536) {
      float4 v = ld4(dtw + (size_t)row * DI + col);
      o = {f2bf(v.x), f2bf(v.y), f2bf(v.z), f2bf(v.w)};
    } else if (row < 1568) {
      float4 v = ld4(xpw + (size_t)(row - 1536) * DI + col);
      o = {f2bf(v.x), f2bf(v.y), f2bf(v.z), f2bf(v.w)};
    }
    *(ushort4*)(d_cat + (size_t)j * 4) = o;
  } else if (i < N4_IN + N4_CAT + N4_OUT) {
    int j = i - N4_IN - N4_CAT;
    float4 v = ld4(opw + (size_t)j * 4);
    ushort4 o = {f2bf(v.x), f2bf(v.y), f2bf(v.z), f2bf(v.w)};
    *(ushort4*)(d_out4 + (size_t)j * 4) = o;
  }
}

// ---------------- bf16 MFMA NT-GEMM: BK=128 (2 K-halves per barrier pair) ----------------
// R15-R18: per-iter stall S (drain+barrier+addr VALU) dominates (MfmaUtil 13%); pipelining
// levers all null/regress. Lever: amortize S over 2x work -- fold two 64-wide K-steps into
// one barrier pair. LDS = 2 halves x (BM+BN) x 64 x 2B = 32KB at 64x64 -> 5 blocks/CU.
// Structure identical to the proven 2-barrier skeleton; per-64-subtile math order unchanged.
template <int EPI, int BM, int BN>
__global__ __launch_bounds__(256) void mfma_gemm(const unsigned short* __restrict__ A,
                                                 const unsigned short* __restrict__ Bw,
                                                 const float* __restrict__ bias,
                                                 const float* __restrict__ resid,
                                                 void* __restrict__ o0v,
                                                 void* __restrict__ o1v, int K, int gx) {
  constexpr int NFI = BM / 32;
  constexpr int NFJ = BN / 32;
  constexpr int NCH = (BM + BN) / 8;  // 16 for 64x64 -> 4 gloads/thread per half
  __shared__ unsigned short As[2][BM * 64];
  __shared__ unsigned short Bs[2][BN * 64];
  int tid = threadIdx.x;
  int lane = tid & 63, w = tid >> 6;
  int wr = w >> 1, wc = w & 1;

  // XCD-chunked bijective swizzle (nwg % 8 == 0 for all launches here)
  int nwg = gx * gridDim.y;
  int orig = blockIdx.y * gx + blockIdx.x;
  int q = nwg >> 3;
  int swz = (orig & 7) * q + (orig >> 3);
  int bm = (swz / gx) * BM, bn = (swz % gx) * BN;

  f32x4 acc[NFI][NFJ];
#pragma unroll
  for (int i = 0; i < NFI; i++)
#pragma unroll
    for (int j = 0; j < NFJ; j++) acc[i][j] = (f32x4){0.f, 0.f, 0.f, 0.f};

  const unsigned short* Ab = A + (size_t)bm * K;
  const unsigned short* Bb = Bw + (size_t)bn * K;
  int lrow = lane >> 3;                          // 0..7
  int kof = ((lane & 7) ^ lrow) * 8;             // inverse-swizzled global source chunk

  auto stage = [&](int kh, int k0) {
#pragma unroll
    for (int ch = w; ch < NCH; ch += 4) {
      if (ch < BM / 8) {
        int row = ch * 8 + lrow;
        gload16(Ab + (size_t)row * K + k0 + kof, &As[kh][ch * 512]);
      } else {
        int row = (ch - BM / 8) * 8 + lrow;
        gload16(Bb + (size_t)row * K + k0 + kof, &Bs[kh][(ch - BM / 8) * 512]);
      }
    }
  };
  auto compute = [&](int kh) {
#pragma unroll
    for (int kk = 0; kk < 2; kk++) {
      int sa = (((kk * 4) + (lane >> 4)) ^ (lane & 7)) * 8;  // swizzled read slot
      bf16x8 af[NFI], bfr[NFJ];
#pragma unroll
      for (int i = 0; i < NFI; i++) {
        int arow = wr * (BM / 2) + i * 16 + (lane & 15);
        af[i] = *(const bf16x8*)&As[kh][arow * 64 + sa];
      }
#pragma unroll
      for (int j = 0; j < NFJ; j++) {
        int brow = wc * (BN / 2) + j * 16 + (lane & 15);
        bfr[j] = *(const bf16x8*)&Bs[kh][brow * 64 + sa];
      }
#pragma unroll
      for (int i = 0; i < NFI; i++)
#pragma unroll
        for (int j = 0; j < NFJ; j++)
          acc[i][j] = __builtin_amdgcn_mfma_f32_16x16x32_bf16(af[i], bfr[j], acc[i][j], 0, 0, 0);
    }
  };

  int nk = K >> 7;  // K-steps of 128
  for (int t = 0; t < nk; t++) {
    __syncthreads();                 // previous iteration's readers done
    stage(0, t << 7);
    stage(1, (t << 7) + 64);         // 8 gloads total in flight
    __syncthreads();                 // compiler drains vmcnt before barrier
    compute(0);
    compute(1);                      // 16 MFMA per wave per barrier pair
  }

#pragma unroll
  for (int i = 0; i < NFI; i++) {
#pragma unroll
    for (int j = 0; j < NFJ; j++) {
      int row0 = bm + wr * (BM / 2) + i * 16 + (lane >> 4) * 4;
      int col = bn + wc * (BN / 2) + j * 16 + (lane & 15);
#pragma unroll
      for (int r = 0; r < 4; r++) {
        float v = acc[i][j][r];
        int row = row0 + r;
        if (EPI == 0) {
          unsigned short* xb = (unsigned short*)o0v;
          unsigned short* z = (unsigned short*)o1v;
          if (col < DI) xb[(size_t)row * DI + col] = f2bf(v);
          else z[(size_t)row * DI + col - DI] = f2bf(v);
        } else if (EPI == 1) {
          unsigned short* delta = (unsigned short*)o0v;  // bf16 delta
          float* bc = (float*)o1v;
          if (col < DI) {
            v += bias[col];
            v = (v > 20.0f) ? v : log1pf(expf(v));
            delta[(size_t)row * DI + col] = f2bf(v);
          } else if (col < DI + 2 * NS) {
            bc[(size_t)row * 32 + col - DI] = v;
          }
        } else {
          float* out = (float*)o0v;
          out[(size_t)row * DM + col] = v + resid[(size_t)row * DM + col];
        }
      }
    }
  }
}

// ---------------- depthwise causal conv (K=4) + bias + SiLU, bf16 in/out ----------------
__global__ __launch_bounds__(192) void conv_silu_kernel(const unsigned short* __restrict__ xb,
                                                        const float* __restrict__ cw,
                                                        const float* __restrict__ cb,
                                                        unsigned short* __restrict__ u) {
  int d = (blockIdx.x * 192 + threadIdx.x) << 2;
  int m = blockIdx.y;
  int t = m & (LL - 1);
  float4 w0 = ld4(cw + d * 4);
  float4 w1 = ld4(cw + d * 4 + 4);
  float4 w2 = ld4(cw + d * 4 + 8);
  float4 w3 = ld4(cw + d * 4 + 12);
  float4 acc = {cb[d], cb[d + 1], cb[d + 2], cb[d + 3]};
#pragma unroll
  for (int tap = 0; tap < 4; tap++) {
    int dt_ = 3 - tap;
    if (t >= dt_) {
      ushort4 xv = *(const ushort4*)(xb + (size_t)(m - dt_) * DI + d);
      float wx = (tap == 0) ? w0.x : (tap == 1) ? w0.y : (tap == 2) ? w0.z : w0.w;
      float wy = (tap == 0) ? w1.x : (tap == 1) ? w1.y : (tap == 2) ? w1.z : w1.w;
      float wz = (tap == 0) ? w2.x : (tap == 1) ? w2.y : (tap == 2) ? w2.z : w2.w;
      float ww = (tap == 0) ? w3.x : (tap == 1) ? w3.y : (tap == 2) ? w3.z : w3.w;
      acc.x += b2f(xv.x) * wx;
      acc.y += b2f(xv.y) * wy;
      acc.z += b2f(xv.z) * wz;
      acc.w += b2f(xv.w) * ww;
    }
  }
  ushort4 o = {f2bf(acc.x / (1.0f + __expf(-acc.x))), f2bf(acc.y / (1.0f + __expf(-acc.y))),
               f2bf(acc.z / (1.0f + __expf(-acc.z))), f2bf(acc.w / (1.0f + __expf(-acc.w)))};
  *(ushort4*)(u + (size_t)m * DI + d) = o;
}

// ---------------- chunked selective scan (CH=32, NC=64 -> 768 blocks/pass), bf16 delta ----------------
__global__ __launch_bounds__(256) void scan_pass1(const unsigned short* __restrict__ delta,
                                                  const unsigned short* __restrict__ u,
                                                  const float* __restrict__ bc,
                                                  const float* __restrict__ A_log,
                                                  float* __restrict__ chunkP,
                                                  float* __restrict__ chunkS) {
  int d = blockIdx.x * 256 + threadIdx.x;
  int c = blockIdx.y;
  int b = blockIdx.z;
  float Acoef[NS];
#pragma unroll
  for (int n = 0; n < NS; n++) Acoef[n] = -__expf(A_log[d * NS + n]);
  __shared__ float sB[CH][NS];
  const float* bcb = bc + (size_t)(b * LL + c * CH) * 32;
  for (int i = threadIdx.x; i < CH * NS; i += 256) sB[i >> 4][i & 15] = bcb[(i >> 4) * 32 + (i & 15)];
  __syncthreads();
  float P[NS], S[NS];
#pragma unroll
  for (int n = 0; n < NS; n++) { P[n] = 1.f; S[n] = 0.f; }
  int m0 = b * LL + c * CH;
  for (int tt = 0; tt < CH; tt++) {
    size_t off = (size_t)(m0 + tt) * DI + d;
    float dl = b2f(delta[off]);
    float ut = b2f(u[off]);
    float dlu = dl * ut;
#pragma unroll
    for (int n = 0; n < NS; n++) {
      float dA = __expf(dl * Acoef[n]);
      S[n] = dA * S[n] + dlu * sB[tt][n];
      P[n] *= dA;
    }
  }
  size_t base = ((size_t)(b * NC + c) * NS) * DI + d;
#pragma unroll
  for (int n = 0; n < NS; n++) {
    chunkP[base + (size_t)n * DI] = P[n];
    chunkS[base + (size_t)n * DI] = S[n];
  }
}

__global__ __launch_bounds__(256) void scan_pass2(const float* __restrict__ chunkP,
                                                  float* __restrict__ chunkS) {
  int id = blockIdx.x * 256 + threadIdx.x;
  int d = id % DI;
  int n = (id / DI) % NS;
  int b = id / (DI * NS);
  float h = 0.f;
  for (int c = 0; c < NC; c++) {
    size_t idx = ((size_t)(b * NC + c) * NS + n) * DI + d;
    float p = chunkP[idx];
    float s = chunkS[idx];
    chunkS[idx] = h;
    h = p * h + s;
  }
}

__global__ __launch_bounds__(256) void scan_pass3(const unsigned short* __restrict__ delta,
                                                  const unsigned short* __restrict__ u,
                                                  const float* __restrict__ bc,
                                                  const float* __restrict__ hIn,
                                                  const float* __restrict__ A_log,
                                                  const float* __restrict__ D_skip,
                                                  const unsigned short* __restrict__ z,
                                                  unsigned short* __restrict__ yg) {
  int d = blockIdx.x * 256 + threadIdx.x;
  int c = blockIdx.y;
  int b = blockIdx.z;
  float Acoef[NS];
#pragma unroll
  for (int n = 0; n < NS; n++) Acoef[n] = -__expf(A_log[d * NS + n]);
  float Dsk = D_skip[d];
  __shared__ float sBC[CH][32];
  const float* bcb = bc + (size_t)(b * LL + c * CH) * 32;
  for (int i = threadIdx.x; i < CH * 32; i += 256) sBC[i >> 5][i & 31] = bcb[i];
  __syncthreads();
  float h[NS];
  size_t base = ((size_t)(b * NC + c) * NS) * DI + d;
#pragma unroll
  for (int n = 0; n < NS; n++) h[n] = hIn[base + (size_t)n * DI];
  int m0 = b * LL + c * CH;
  for (int tt = 0; tt < CH; tt++) {
    size_t m = (size_t)(m0 + tt);
    size_t off = m * DI + d;
    float dl = b2f(delta[off]);
    float ut = b2f(u[off]);
    float dlu = dl * ut;
    float yt = 0.f;
#pragma unroll
    for (int n = 0; n < NS; n++) {
      float dA = __expf(dl * Acoef[n]);
      h[n] = dA * h[n] + dlu * sBC[tt][n];
      yt += h[n] * sBC[tt][16 + n];
    }
    float zv = b2f(z[m * DI + d]);
    float sz = zv / (1.0f + __expf(-zv));
    yg[m * DI + d] = f2bf((yt + ut * Dsk) * sz);
  }
}

extern "C" void kernel_launch(void* const* d_in, const int* in_sizes, int n_in,
                              void* d_out, int out_size, void* d_ws, size_t ws_size,
                              hipStream_t stream) {
  const float* x = (const float*)d_in[0];
  const float* norm_w = (const float*)d_in[1];
  const float* in_proj_w = (const float*)d_in[2];
  const float* conv_w = (const float*)d_in[3];
  const float* conv_b = (const float*)d_in[4];
  const float* x_proj_w = (const float*)d_in[5];
  const float* dt_proj_w = (const float*)d_in[6];
  const float* dt_proj_b = (const float*)d_in[7];
  const float* A_log = (const float*)d_in[8];
  const float* D_skip = (const float*)d_in[9];
  const float* out_proj_w = (const float*)d_in[10];
  float* out = (float*)d_out;

  float* ws = (float*)d_ws;
  unsigned short* xb_bf = (unsigned short*)ws;                 // -> 3,145,728 fl
  unsigned short* z_bf = (unsigned short*)(ws + 3145728);      // -> 6,291,456
  unsigned short* u_bf = (unsigned short*)(ws + 6291456);      // -> 9,437,184
  unsigned short* delta_bf = (unsigned short*)(ws + 9437184);  // bf16; slot -> 15,728,640
  unsigned short* ygbf = (unsigned short*)(ws + 15728640);     // -> 17,301,504
  unsigned short* wbf_in = (unsigned short*)(ws + 18874368);   // -> 20,054,016
  unsigned short* wbf_cat = (unsigned short*)(ws + 20054016);  // -> 21,331,968
  unsigned short* wbf_out = (unsigned short*)(ws + 21331968);  // -> 21,921,792
  float* chunkP = ws + 21921792;                               // -> 25,067,520
  float* chunkS = ws + 25067520;                               // -> 28,213,248 (112.9 MB)
  unsigned short* xn_bf = (unsigned short*)d_out;  // 4096*768 bf16
  float* bcb = (float*)d_out + 1572864;            // 4096*32 f32

  prep_kernel<<<CVT_BLOCKS + 4096, 256, 0, stream>>>(in_proj_w, dt_proj_w, x_proj_w,
                                                     out_proj_w, wbf_in, wbf_cat, wbf_out,
                                                     x, norm_w, xn_bf);

  // xb|z = rmsnorm(x) @ in_proj_w^T   (M=4096, N=3072, K=768), 64x64 -> 3072 blocks, nk=6
  mfma_gemm<0, 64, 64><<<dim3(48, 64), 256, 0, stream>>>(xn_bf, wbf_in, nullptr, nullptr,
                                                         xb_bf, z_bf, DM, 48);

  conv_silu_kernel<<<dim3(2, 4096), 192, 0, stream>>>(xb_bf, conv_w, conv_b, u_bf);

  // delta|bc = u @ [dt_proj_w; x_proj_w]^T  (M=4096, N=1664, K=1536), nk=12 -> 1664 blocks
  mfma_gemm<1, 64, 64><<<dim3(26, 64), 256, 0, stream>>>(u_bf, wbf_cat, dt_proj_b, nullptr,
                                                         delta_bf, bcb, DI, 26);

  scan_pass1<<<dim3(6, NC, 2), 256, 0, stream>>>(delta_bf, u_bf, bcb, A_log, chunkP, chunkS);
  scan_pass2<<<192, 256, 0, stream>>>(chunkP, chunkS);
  scan_pass3<<<dim3(6, NC, 2), 256, 0, stream>>>(delta_bf, u_bf, bcb, chunkS, A_log, D_skip,
                                                 z_bf, ygbf);

  // out = yg @ out_proj_w^T + x  (M=4096, N=768, K=1536), nk=12 -> 768 blocks
  mfma_gemm<2, 64, 64><<<dim3(12, 64), 256, 0, stream>>>(ygbf, wbf_out, nullptr, x, out,
                                                         nullptr, DI, 12);
}